// Round 10
// baseline (28.774 us; speedup 1.0000x reference)
//
#include <hip/hip_runtime.h>

// DRAM-stream-locality probe with the PROVEN R8 chunk body (26.0us, passed).
// Each wave processes 4 consecutive chunks of 64 batches (256 consecutive
// batches/wave, 1024/block, grid=512 -> all blocks resident at 4 blocks/CU).
// Concurrent DRAM streams drop 4x (12K -> 3K); per-stream sequential run
// grows 4x (2.3KB -> 9.2KB per array per wave). Per-chunk body identical to
// R8: single-burst 12x float4 staged loads -> wave-private LDS -> compute ->
// interleaved out-stage -> coalesced float4 flush. Zero __syncthreads();
// LDS buffer reuse across chunks is safe by in-wave DS ordering (R8-proven).

#define CHUNKS 4
#define INV2PI 0.15915494309189535f

__global__ __launch_bounds__(256, 4)
void sun_diffuse_kernel(const float* __restrict__ U0_re, const float* __restrict__ U0_im,
                        const float* __restrict__ xs,
                        const float* __restrict__ V_re, const float* __restrict__ V_im,
                        float* __restrict__ out, int nb)
{
    // per-wave slice: Vre[576] Vim[576] U0re[576] U0im[576] = 2304 f32 (9216 B)
    __shared__ __align__(16) float smem[4][2304];

    const int tid  = threadIdx.x;
    const int w    = tid >> 6;
    const int lane = tid & 63;

    float* S     = smem[w];
    float* sVre  = S;
    float* sVim  = S + 576;
    float* sU0re = S + 1152;
    float* sU0im = S + 1728;

    const int wstart = blockIdx.x * (64 * 4 * CHUNKS) + w * (64 * CHUNKS);

#pragma unroll 1
    for (int c = 0; c < CHUNKS; ++c) {
        const int wb0 = wstart + c * 64;               // first batch of this chunk
        const int nw  = min(max(nb - wb0, 0), 64);

        if (nw == 64) {
            // ---- one burst: 12 coalesced float4 loads (wb0*36 B 16B-aligned) ----
            const float4* g0 = reinterpret_cast<const float4*>(V_re  + (size_t)wb0 * 9);
            const float4* g1 = reinterpret_cast<const float4*>(V_im  + (size_t)wb0 * 9);
            const float4* g2 = reinterpret_cast<const float4*>(U0_re + (size_t)wb0 * 9);
            const float4* g3 = reinterpret_cast<const float4*>(U0_im + (size_t)wb0 * 9);
            float4* s0 = reinterpret_cast<float4*>(sVre);
            float4* s1 = reinterpret_cast<float4*>(sVim);
            float4* s2 = reinterpret_cast<float4*>(sU0re);
            float4* s3 = reinterpret_cast<float4*>(sU0im);
#pragma unroll
            for (int r = 0; r < 3; ++r) {
                const int i = lane + r * 64;           // 144 = 2*64 + 16
                if (i < 144) { s0[i] = g0[i]; s1[i] = g1[i]; s2[i] = g2[i]; s3[i] = g3[i]; }
            }

            // ---- phases: per-lane xs, HW sin/cos in revolutions ----
            const size_t xb = (size_t)(wb0 + lane) * 3;
            float pr[3], pi[3];
#pragma unroll
            for (int k = 0; k < 3; ++k) {
                const float rv = xs[xb + k] * INV2PI;
                pr[k] = __builtin_amdgcn_cosf(rv);
                pi[k] = __builtin_amdgcn_sinf(rv);
            }

            float vr[9], vi[9], ur[9], ui[9];
#pragma unroll
            for (int m = 0; m < 9; ++m) {
                vr[m] = sVre [lane * 9 + m];
                vi[m] = sVim [lane * 9 + m];
                ur[m] = sU0re[lane * 9 + m];
                ui[m] = sU0im[lane * 9 + m];
            }

            // E_ij = sum_k p_k * V_ik * conj(V_jk)
            float Er[9], Ei[9];
#pragma unroll
            for (int i = 0; i < 3; ++i) {
#pragma unroll
                for (int j = 0; j < 3; ++j) {
                    float er = 0.f, ei = 0.f;
#pragma unroll
                    for (int k = 0; k < 3; ++k) {
                        float wr = pr[k] * vr[i * 3 + k] - pi[k] * vi[i * 3 + k];
                        float wi = pr[k] * vi[i * 3 + k] + pi[k] * vr[i * 3 + k];
                        er += wr * vr[j * 3 + k] + wi * vi[j * 3 + k];
                        ei += wi * vr[j * 3 + k] - wr * vi[j * 3 + k];
                    }
                    Er[i * 3 + j] = er; Ei[i * 3 + j] = ei;
                }
            }

            // Ut = E @ U0, stage interleaved re/im into reused slice head
            float2* S2 = reinterpret_cast<float2*>(S);
#pragma unroll
            for (int i = 0; i < 3; ++i) {
#pragma unroll
                for (int j = 0; j < 3; ++j) {
                    float r = 0.f, im = 0.f;
#pragma unroll
                    for (int k = 0; k < 3; ++k) {
                        r  += Er[i * 3 + k] * ur[k * 3 + j] - Ei[i * 3 + k] * ui[k * 3 + j];
                        im += Er[i * 3 + k] * ui[k * 3 + j] + Ei[i * 3 + k] * ur[k * 3 + j];
                    }
                    S2[lane * 9 + i * 3 + j] = make_float2(r, im);
                }
            }

            // coalesced flush: 288 float4 (in-wave DS order: reads follow writes)
            float4* gO = reinterpret_cast<float4*>(out + (size_t)wb0 * 18);
            const float4* s4 = reinterpret_cast<const float4*>(S);
#pragma unroll
            for (int r = 0; r < 5; ++r) {
                const int i = lane + r * 64;           // 288 = 4*64 + 32
                if (i < 288) gO[i] = s4[i];
            }
        } else if (nw > 0 && lane < nw) {
            // tail (unused at B=524288): per-lane direct path
            const size_t mb = (size_t)(wb0 + lane) * 9;
            const size_t xb = (size_t)(wb0 + lane) * 3;
            float vr[9], vi[9], ur[9], ui[9];
#pragma unroll
            for (int m = 0; m < 9; ++m) {
                vr[m] = V_re[mb + m];  vi[m] = V_im[mb + m];
                ur[m] = U0_re[mb + m]; ui[m] = U0_im[mb + m];
            }
            float pr[3], pi[3];
#pragma unroll
            for (int k = 0; k < 3; ++k) {
                const float rv = xs[xb + k] * INV2PI;
                pr[k] = __builtin_amdgcn_cosf(rv);
                pi[k] = __builtin_amdgcn_sinf(rv);
            }
            float Er[9], Ei[9];
#pragma unroll
            for (int i = 0; i < 3; ++i)
#pragma unroll
                for (int j = 0; j < 3; ++j) {
                    float er = 0.f, ei = 0.f;
#pragma unroll
                    for (int k = 0; k < 3; ++k) {
                        float wr = pr[k] * vr[i * 3 + k] - pi[k] * vi[i * 3 + k];
                        float wi = pr[k] * vi[i * 3 + k] + pi[k] * vr[i * 3 + k];
                        er += wr * vr[j * 3 + k] + wi * vi[j * 3 + k];
                        ei += wi * vr[j * 3 + k] - wr * vi[j * 3 + k];
                    }
                    Er[i * 3 + j] = er; Ei[i * 3 + j] = ei;
                }
#pragma unroll
            for (int i = 0; i < 3; ++i)
#pragma unroll
                for (int j = 0; j < 3; ++j) {
                    float r = 0.f, im = 0.f;
#pragma unroll
                    for (int k = 0; k < 3; ++k) {
                        r  += Er[i * 3 + k] * ur[k * 3 + j] - Ei[i * 3 + k] * ui[k * 3 + j];
                        im += Er[i * 3 + k] * ui[k * 3 + j] + Ei[i * 3 + k] * ur[k * 3 + j];
                    }
                    out[((size_t)(wb0 + lane) * 9 + i * 3 + j) * 2]     = r;
                    out[((size_t)(wb0 + lane) * 9 + i * 3 + j) * 2 + 1] = im;
                }
        }
    }
}

extern "C" void kernel_launch(void* const* d_in, const int* in_sizes, int n_in,
                              void* d_out, int out_size, void* d_ws, size_t ws_size,
                              hipStream_t stream) {
    const float* U0_re = (const float*)d_in[0];
    const float* U0_im = (const float*)d_in[1];
    const float* xs    = (const float*)d_in[2];
    const float* V_re  = (const float*)d_in[3];
    const float* V_im  = (const float*)d_in[4];
    float* out = (float*)d_out;

    const int nb = in_sizes[2] / 3;
    const int bpb = 64 * 4 * CHUNKS;                  // 1024 batches per block
    const int grid = (nb + bpb - 1) / bpb;
    sun_diffuse_kernel<<<grid, 256, 0, stream>>>(U0_re, U0_im, xs, V_re, V_im, out, nb);
}